// Round 1
// baseline (278.533 us; speedup 1.0000x reference)
//
#include <hip/hip_runtime.h>
#include <hip/hip_bf16.h>
#include <math.h>

#define B 4
#define L 1024
#define D 256
#define H 8
#define HD 64

// workspace layout (float offsets)
#define Q_OFF   0
#define KT_OFF  (H*B*L*HD)             // 2097152
#define VR_OFF  (KT_OFF + H*B*L*HD)    // 4194304
#define T_OFF   (VR_OFF + H*B*L)       // 4227072
// total floats: T_OFF + H*B*L = 4259840  (~16.3 MB)

// ---------------------------------------------------------------------------
// Kernel 1: xpe = x+pe;  Q = xpe@Wq + bq  -> [hb][l][hd]
//           K = xpe@Wk + bk              -> interleaved [hb][g=hd/4][l][4]
//           Vr[hb][k] = sigmoid(x@Wv)[h,b,L-1-k]
// 8 rows per block, 256 threads (each thread: 2 q cols + 2 k cols x 8 rows)
// ---------------------------------------------------------------------------
__global__ __launch_bounds__(256) void qkv_kernel(
    const float* __restrict__ x, const float* __restrict__ Wq,
    const float* __restrict__ bq, const float* __restrict__ Wk,
    const float* __restrict__ bk, const float* __restrict__ Wv,
    const float* __restrict__ pe, float* __restrict__ ws)
{
  __shared__ float xs[8][D];   // x rows
  __shared__ float xp[8][D];   // x+pe rows
  const int tid = threadIdx.x;
  const int r0 = blockIdx.x * 8;

  for (int idx = tid; idx < 8 * D; idx += 256) {
    int rr = idx >> 8, c = idx & 255;
    int gr = r0 + rr;
    int l = gr & 1023;
    float xv = x[gr * D + c];
    xs[rr][c] = xv;
    xp[rr][c] = xv + pe[l * D + c];
  }
  __syncthreads();

  // v = sigmoid(x @ Wv), stored reversed along l
  if (tid < 64) {
    int rr = tid >> 3, h = tid & 7;
    float acc = 0.f;
    for (int d = 0; d < D; ++d) acc += xs[rr][d] * Wv[d * H + h];
    float v = 1.f / (1.f + __expf(-acc));
    int gr = r0 + rr;
    int b = gr >> 10, l = gr & 1023;
    ws[VR_OFF + (h * B + b) * L + (L - 1 - l)] = v;
  }

  float accq0[8], accq1[8], acck0[8], acck1[8];
#pragma unroll
  for (int r = 0; r < 8; ++r) { accq0[r] = 0.f; accq1[r] = 0.f; acck0[r] = 0.f; acck1[r] = 0.f; }

  const int c0 = tid, c1 = tid + 256;
  for (int d = 0; d < D; ++d) {
    float wq0 = Wq[d * 512 + c0], wq1 = Wq[d * 512 + c1];
    float wk0 = Wk[d * 512 + c0], wk1 = Wk[d * 512 + c1];
#pragma unroll
    for (int r = 0; r < 8; ++r) {
      float xv = xp[r][d];
      accq0[r] += xv * wq0; accq1[r] += xv * wq1;
      acck0[r] += xv * wk0; acck1[r] += xv * wk1;
    }
  }

  {
    int h = c0 >> 6, hd = c0 & 63;
    float bqv = bq[c0], bkv = bk[c0];
#pragma unroll
    for (int r = 0; r < 8; ++r) {
      int gr = r0 + r;
      int b = gr >> 10, l = gr & 1023;
      int hb = h * B + b;
      ws[Q_OFF + ((hb * L + l) * HD) + hd] = accq0[r] + bqv;
      ws[KT_OFF + ((hb * 16 + (hd >> 2)) * L + l) * 4 + (hd & 3)] = acck0[r] + bkv;
    }
  }
  {
    int h = c1 >> 6, hd = c1 & 63;
    float bqv = bq[c1], bkv = bk[c1];
#pragma unroll
    for (int r = 0; r < 8; ++r) {
      int gr = r0 + r;
      int b = gr >> 10, l = gr & 1023;
      int hb = h * B + b;
      ws[Q_OFF + ((hb * L + l) * HD) + hd] = accq1[r] + bqv;
      ws[KT_OFF + ((hb * 16 + (hd >> 2)) * L + l) * 4 + (hd & 3)] = acck1[r] + bkv;
    }
  }
}

// ---------------------------------------------------------------------------
// Kernel 2: per (hb, q-chunk of 128): scores -> softmax -> diagonal accum T
// block = 256 thr (4 waves). 16 passes x 8 q-rows.
// ---------------------------------------------------------------------------
__global__ __launch_bounds__(256) void attn_kernel(float* __restrict__ ws)
{
  __shared__ float sbuf[8][1024];   // 32 KB scores
  __shared__ float Tw[4][1024];     // 16 KB per-wave diagonal accum
  __shared__ float qbuf[8][64];     //  2 KB
  __shared__ float vbuf[1024];      //  4 KB

  const int tid = threadIdx.x;
  const int hb = blockIdx.x >> 3;
  const int q0 = (blockIdx.x & 7) << 7;
  const int w = tid >> 6, lane = tid & 63;

  for (int i = tid; i < 4096; i += 256) (&Tw[0][0])[i] = 0.f;
  for (int i = tid; i < 1024; i += 256) vbuf[i] = ws[VR_OFF + hb * 1024 + i];
  __syncthreads();

  const float4* __restrict__ K4 = (const float4*)(ws + KT_OFF) + (size_t)hb * 16 * 1024;
  const float* __restrict__ Qb = ws + Q_OFF + (size_t)hb * 1024 * 64;

  for (int pass = 0; pass < 16; ++pass) {
    const int qi0 = q0 + pass * 8;
    for (int idx = tid; idx < 512; idx += 256) {
      int r = idx >> 6, c = idx & 63;
      qbuf[r][c] = Qb[(qi0 + r) * 64 + c];
    }
    __syncthreads();

    float acc[4][8];
#pragma unroll
    for (int j = 0; j < 4; ++j)
#pragma unroll
      for (int r = 0; r < 8; ++r) acc[j][r] = 0.f;

    for (int g = 0; g < 16; ++g) {
      float4 qv[8];
#pragma unroll
      for (int r = 0; r < 8; ++r) qv[r] = ((const float4*)qbuf[r])[g];
#pragma unroll
      for (int j = 0; j < 4; ++j) {
        float4 kv = K4[g * 1024 + tid + j * 256];
#pragma unroll
        for (int r = 0; r < 8; ++r)
          acc[j][r] += qv[r].x * kv.x + qv[r].y * kv.y + qv[r].z * kv.z + qv[r].w * kv.w;
      }
    }
#pragma unroll
    for (int j = 0; j < 4; ++j)
#pragma unroll
      for (int r = 0; r < 8; ++r)
        sbuf[r][tid + j * 256] = acc[j][r] * 0.125f;
    __syncthreads();

    // softmax + diagonal accumulation: wave w handles rows 2w, 2w+1
    for (int rr = 0; rr < 2; ++rr) {
      const int r = 2 * w + rr;
      const int qi = qi0 + r;
      float m = -1e30f;
#pragma unroll
      for (int i = 0; i < 16; ++i) m = fmaxf(m, sbuf[r][lane + 64 * i]);
#pragma unroll
      for (int off = 32; off > 0; off >>= 1) m = fmaxf(m, __shfl_xor(m, off));
      float sum = 0.f;
#pragma unroll
      for (int i = 0; i < 16; ++i) {
        int kk = lane + 64 * i;
        float e = __expf(sbuf[r][kk] - m);
        sbuf[r][kk] = e;
        sum += e;
      }
#pragma unroll
      for (int off = 32; off > 0; off >>= 1) sum += __shfl_xor(sum, off);
      float inv = 1.f / sum;
#pragma unroll
      for (int i = 0; i < 16; ++i) {
        int kk = lane + 64 * i;
        if (kk >= qi) Tw[w][kk - qi] += sbuf[r][kk] * inv * vbuf[kk];
      }
    }
    __syncthreads();
  }

  for (int j = tid; j < 1024; j += 256) {
    float s = Tw[0][j] + Tw[1][j] + Tw[2][j] + Tw[3][j];
    atomicAdd(&ws[T_OFF + hb * 1024 + j], s);
  }
}

// ---------------------------------------------------------------------------
// Kernel 3: out[b,j,h] = (T[j-1]+T[j]+T[j+1]) / cnt[j]
// ---------------------------------------------------------------------------
__global__ __launch_bounds__(256) void out_kernel(const float* __restrict__ ws,
                                                  float* __restrict__ out)
{
  int o = blockIdx.x * 256 + threadIdx.x;
  if (o >= B * L * H) return;
  int h = o & 7;
  int j = (o >> 3) & 1023;
  int b = o >> 13;
  const float* T = ws + T_OFF + (h * B + b) * 1024;
  float s = T[j];
  float cnt = 3.f;
  if (j > 0) s += T[j - 1];
  if (j < 1023) s += T[j + 1];
  if (j == 0 || j == 1023) cnt = 2.f;
  out[o] = s / cnt;
}

extern "C" void kernel_launch(void* const* d_in, const int* in_sizes, int n_in,
                              void* d_out, int out_size, void* d_ws, size_t ws_size,
                              hipStream_t stream)
{
  const float* x  = (const float*)d_in[0];
  const float* Wq = (const float*)d_in[1];
  const float* bq = (const float*)d_in[2];
  const float* Wk = (const float*)d_in[3];
  const float* bk = (const float*)d_in[4];
  const float* Wv = (const float*)d_in[5];
  const float* pe = (const float*)d_in[6];
  float* ws = (float*)d_ws;
  float* out = (float*)d_out;

  hipMemsetAsync(ws + T_OFF, 0, H * B * L * sizeof(float), stream);
  qkv_kernel<<<dim3((B * L) / 8), dim3(256), 0, stream>>>(x, Wq, bq, Wk, bk, Wv, pe, ws);
  attn_kernel<<<dim3(H * B * 8), dim3(256), 0, stream>>>(ws);
  out_kernel<<<dim3((B * L * H + 255) / 256), dim3(256), 0, stream>>>(ws, out);
}

// Round 2
// 160.131 us; speedup vs baseline: 1.7394x; 1.7394x over previous
//
#include <hip/hip_runtime.h>
#include <hip/hip_bf16.h>
#include <math.h>

#define B 4
#define L 1024
#define D 256
#define H 8
#define HD 64

// workspace layout (float offsets)
#define Q_OFF   0
#define KT_OFF  (H*B*L*HD)             // 2097152
#define VR_OFF  (KT_OFF + H*B*L*HD)    // 4194304 (K stored bf16, region half-used)
#define T_OFF   (VR_OFF + H*B*L)       // 4227072
// total floats: T_OFF + H*B*L = 4259840  (~16.3 MB)

__device__ __forceinline__ float bf16_lo(unsigned int u) {
  unsigned int v = u << 16;
  return __uint_as_float(v);
}
__device__ __forceinline__ float bf16_hi(unsigned int u) {
  unsigned int v = u & 0xFFFF0000u;
  return __uint_as_float(v);
}

// ---------------------------------------------------------------------------
// Kernel 1: xpe = x+pe;  Q = xpe@Wq + bq  -> [hb][l][hd] fp32
//           K = xpe@Wk + bk              -> bf16 interleaved [hb][g=hd/4][l][4]
//           Vr[hb][k] = sigmoid(x@Wv)[h,b,L-1-k]
// ---------------------------------------------------------------------------
__global__ __launch_bounds__(256) void qkv_kernel(
    const float* __restrict__ x, const float* __restrict__ Wq,
    const float* __restrict__ bq, const float* __restrict__ Wk,
    const float* __restrict__ bk, const float* __restrict__ Wv,
    const float* __restrict__ pe, float* __restrict__ ws)
{
  __shared__ float xs[8][D];   // x rows
  __shared__ float xp[8][D];   // x+pe rows
  const int tid = threadIdx.x;
  const int r0 = blockIdx.x * 8;

  for (int idx = tid; idx < 8 * D; idx += 256) {
    int rr = idx >> 8, c = idx & 255;
    int gr = r0 + rr;
    int l = gr & 1023;
    float xv = x[gr * D + c];
    xs[rr][c] = xv;
    xp[rr][c] = xv + pe[l * D + c];
  }
  __syncthreads();

  // v = sigmoid(x @ Wv), stored reversed along l
  if (tid < 64) {
    int rr = tid >> 3, h = tid & 7;
    float acc = 0.f;
    for (int d = 0; d < D; ++d) acc += xs[rr][d] * Wv[d * H + h];
    float v = 1.f / (1.f + __expf(-acc));
    int gr = r0 + rr;
    int b = gr >> 10, l = gr & 1023;
    ws[VR_OFF + (h * B + b) * L + (L - 1 - l)] = v;
  }

  float accq0[8], accq1[8], acck0[8], acck1[8];
#pragma unroll
  for (int r = 0; r < 8; ++r) { accq0[r] = 0.f; accq1[r] = 0.f; acck0[r] = 0.f; acck1[r] = 0.f; }

  const int c0 = tid, c1 = tid + 256;
  for (int d = 0; d < D; ++d) {
    float wq0 = Wq[d * 512 + c0], wq1 = Wq[d * 512 + c1];
    float wk0 = Wk[d * 512 + c0], wk1 = Wk[d * 512 + c1];
#pragma unroll
    for (int r = 0; r < 8; ++r) {
      float xv = xp[r][d];
      accq0[r] += xv * wq0; accq1[r] += xv * wq1;
      acck0[r] += xv * wk0; acck1[r] += xv * wk1;
    }
  }

  __hip_bfloat16* KT = (__hip_bfloat16*)(ws + KT_OFF);
  {
    int h = c0 >> 6, hd = c0 & 63;
    float bqv = bq[c0], bkv = bk[c0];
#pragma unroll
    for (int r = 0; r < 8; ++r) {
      int gr = r0 + r;
      int b = gr >> 10, l = gr & 1023;
      int hb = h * B + b;
      ws[Q_OFF + ((hb * L + l) * HD) + hd] = accq0[r] + bqv;
      KT[(((hb * 16 + (hd >> 2)) * L + l) << 2) + (hd & 3)] = __float2bfloat16(acck0[r] + bkv);
    }
  }
  {
    int h = c1 >> 6, hd = c1 & 63;
    float bqv = bq[c1], bkv = bk[c1];
#pragma unroll
    for (int r = 0; r < 8; ++r) {
      int gr = r0 + r;
      int b = gr >> 10, l = gr & 1023;
      int hb = h * B + b;
      ws[Q_OFF + ((hb * L + l) * HD) + hd] = accq1[r] + bqv;
      KT[(((hb * 16 + (hd >> 2)) * L + l) << 2) + (hd & 3)] = __float2bfloat16(acck1[r] + bkv);
    }
  }
}

// ---------------------------------------------------------------------------
// Kernel 2: per (hb, q-chunk of 64): scores -> softmax -> diagonal accum T
// grid = 512 blocks, XCD-remapped so all chunks of one hb share an XCD.
// block = 256 thr (4 waves); 8 passes x 8 q-rows.
// ---------------------------------------------------------------------------
__global__ __launch_bounds__(256) void attn_kernel(float* __restrict__ ws)
{
  __shared__ float sbuf[8][1024];   // 32 KB scores
  __shared__ float Tw[4][1024];     // 16 KB per-wave diagonal accum
  __shared__ float qbuf[8][64];     //  2 KB
  __shared__ float vbuf[1024];      //  4 KB

  const int tid = threadIdx.x;
  // XCD-aware decode: i%8 == hb%8 so all 16 chunks of an hb land on one XCD
  const int i = blockIdx.x;
  const int hb = ((i >> 7) << 3) | (i & 7);
  const int q0 = ((i >> 3) & 15) << 6;
  const int w = tid >> 6, lane = tid & 63;

  for (int idx = tid; idx < 4096; idx += 256) (&Tw[0][0])[idx] = 0.f;
  for (int idx = tid; idx < 1024; idx += 256) vbuf[idx] = ws[VR_OFF + hb * 1024 + idx];
  __syncthreads();

  // K: bf16 groups of 4, [hb][g][l][4] -> uint2 per (g,l)
  const uint2* __restrict__ K2 = (const uint2*)((const __hip_bfloat16*)(ws + KT_OFF)) + (size_t)hb * 16 * 1024;
  const float* __restrict__ Qb = ws + Q_OFF + (size_t)hb * 1024 * 64;

  for (int pass = 0; pass < 8; ++pass) {
    const int qi0 = q0 + pass * 8;
    for (int idx = tid; idx < 512; idx += 256) {
      int r = idx >> 6, c = idx & 63;
      qbuf[r][c] = Qb[(qi0 + r) * 64 + c];
    }
    __syncthreads();

    float acc[4][8];
#pragma unroll
    for (int j = 0; j < 4; ++j)
#pragma unroll
      for (int r = 0; r < 8; ++r) acc[j][r] = 0.f;

    for (int g = 0; g < 16; ++g) {
      float4 qv[8];
#pragma unroll
      for (int r = 0; r < 8; ++r) qv[r] = ((const float4*)qbuf[r])[g];
#pragma unroll
      for (int j = 0; j < 4; ++j) {
        uint2 kv = K2[g * 1024 + tid + j * 256];
        float k0 = bf16_lo(kv.x), k1 = bf16_hi(kv.x);
        float k2 = bf16_lo(kv.y), k3 = bf16_hi(kv.y);
#pragma unroll
        for (int r = 0; r < 8; ++r)
          acc[j][r] += qv[r].x * k0 + qv[r].y * k1 + qv[r].z * k2 + qv[r].w * k3;
      }
    }
#pragma unroll
    for (int j = 0; j < 4; ++j)
#pragma unroll
      for (int r = 0; r < 8; ++r)
        sbuf[r][tid + j * 256] = acc[j][r] * 0.125f;
    __syncthreads();

    // softmax + diagonal accumulation: wave w handles rows 2w, 2w+1
    for (int rr = 0; rr < 2; ++rr) {
      const int r = 2 * w + rr;
      const int qi = qi0 + r;
      float m = -1e30f;
#pragma unroll
      for (int ii = 0; ii < 16; ++ii) m = fmaxf(m, sbuf[r][lane + 64 * ii]);
#pragma unroll
      for (int off = 32; off > 0; off >>= 1) m = fmaxf(m, __shfl_xor(m, off));
      float sum = 0.f;
#pragma unroll
      for (int ii = 0; ii < 16; ++ii) {
        int kk = lane + 64 * ii;
        float e = __expf(sbuf[r][kk] - m);
        sbuf[r][kk] = e;
        sum += e;
      }
#pragma unroll
      for (int off = 32; off > 0; off >>= 1) sum += __shfl_xor(sum, off);
      float inv = 1.f / sum;
#pragma unroll
      for (int ii = 0; ii < 16; ++ii) {
        int kk = lane + 64 * ii;
        if (kk >= qi) Tw[w][kk - qi] += sbuf[r][kk] * inv * vbuf[kk];
      }
    }
    __syncthreads();
  }

  for (int j = tid; j < 1024; j += 256) {
    float s = Tw[0][j] + Tw[1][j] + Tw[2][j] + Tw[3][j];
    atomicAdd(&ws[T_OFF + hb * 1024 + j], s);
  }
}

// ---------------------------------------------------------------------------
// Kernel 3: out[b,j,h] = (T[j-1]+T[j]+T[j+1]) / cnt[j]
// ---------------------------------------------------------------------------
__global__ __launch_bounds__(256) void out_kernel(const float* __restrict__ ws,
                                                  float* __restrict__ out)
{
  int o = blockIdx.x * 256 + threadIdx.x;
  if (o >= B * L * H) return;
  int h = o & 7;
  int j = (o >> 3) & 1023;
  int b = o >> 13;
  const float* T = ws + T_OFF + (h * B + b) * 1024;
  float s = T[j];
  float cnt = 3.f;
  if (j > 0) s += T[j - 1];
  if (j < 1023) s += T[j + 1];
  if (j == 0 || j == 1023) cnt = 2.f;
  out[o] = s / cnt;
}

extern "C" void kernel_launch(void* const* d_in, const int* in_sizes, int n_in,
                              void* d_out, int out_size, void* d_ws, size_t ws_size,
                              hipStream_t stream)
{
  const float* x  = (const float*)d_in[0];
  const float* Wq = (const float*)d_in[1];
  const float* bq = (const float*)d_in[2];
  const float* Wk = (const float*)d_in[3];
  const float* bk = (const float*)d_in[4];
  const float* Wv = (const float*)d_in[5];
  const float* pe = (const float*)d_in[6];
  float* ws = (float*)d_ws;
  float* out = (float*)d_out;

  hipMemsetAsync(ws + T_OFF, 0, H * B * L * sizeof(float), stream);
  qkv_kernel<<<dim3((B * L) / 8), dim3(256), 0, stream>>>(x, Wq, bq, Wk, bk, Wv, pe, ws);
  attn_kernel<<<dim3(512), dim3(256), 0, stream>>>(ws);
  out_kernel<<<dim3((B * L * H + 255) / 256), dim3(256), 0, stream>>>(ws, out);
}